// Round 9
// baseline (459.488 us; speedup 1.0000x reference)
//
#include <hip/hip_runtime.h>
#include <hip/hip_bf16.h>

typedef _Float16 half8 __attribute__((ext_vector_type(8)));
typedef _Float16 half4v __attribute__((ext_vector_type(4)));
typedef float floatx4 __attribute__((ext_vector_type(4)));
typedef float floatx16 __attribute__((ext_vector_type(16)));

// ---------------------------------------------------------------------------
// Swizzled LDS layouts (chunk = 8 halfs = 16B, rotated by row).
// act buffer: 64x256 fp16 (32 KiB, single, in-place read->barrier->write).
// x buffer: 64x64 fp16 (8 KiB). Total 40960 B.
// ---------------------------------------------------------------------------
__device__ __forceinline__ int swz(int row, int col) {
    return row * 256 + ((((col >> 3) + row) & 31) << 3) + (col & 7);
}
__device__ __forceinline__ int xswz(int row, int col) {
    return row * 64 + ((((col >> 3) + row) & 7) << 3) + (col & 7);
}

// ---------------------------------------------------------------------------
// Weight pre-pack (numerically proven R5-R8): fp32 (K,N) row-major -> fp16
// fragment order; lane L holds W[kt*16 + 8*(L>>5) + j][nt*32 + (L&31)].
// Fed to the MFMA *A* operand (identical register layout) so D = C^T.
// K zero-padded: L1 39->64 (KT=4), L5 295->320 (KT=20), others 256 (KT=16).
// L9 N 4->32. Tile starts (1KB tiles): {0,32,160,288,416,576,704,832,960},
// total 976 tiles = 999424 B in d_ws.
// ---------------------------------------------------------------------------
__global__ void pack_w32(const float* __restrict__ w1, const float* __restrict__ w2,
                         const float* __restrict__ w3, const float* __restrict__ w4,
                         const float* __restrict__ w5, const float* __restrict__ w6,
                         const float* __restrict__ w7, const float* __restrict__ w8,
                         const float* __restrict__ w9, _Float16* __restrict__ dst) {
    const int tileStart[10] = {0, 32, 160, 288, 416, 576, 704, 832, 960, 976};
    const int Ks[9] = {39, 256, 256, 256, 295, 256, 256, 256, 256};
    const int Ns[9] = {256, 256, 256, 256, 256, 256, 256, 256, 4};
    const int Tn[9] = {8, 8, 8, 8, 8, 8, 8, 8, 1};
    const float* ws[9] = {w1, w2, w3, w4, w5, w6, w7, w8, w9};

    int g = blockIdx.x * blockDim.x + threadIdx.x;
    int tile = g >> 6, lane = g & 63;
    if (tile >= 976) return;
    int layer = 0;
    while (tile >= tileStart[layer + 1]) layer++;
    int t = tile - tileStart[layer];
    int tn = Tn[layer];
    int kt = t / tn, nt = t - kt * tn;
    int k0 = kt * 16 + (lane >> 5) * 8;
    int n = nt * 32 + (lane & 31);
    const float* w = ws[layer];
    int K = Ks[layer], N = Ns[layer];
    _Float16 v[8];
#pragma unroll
    for (int j = 0; j < 8; j++) {
        int k = k0 + j;
        v[j] = (k < K && n < N) ? (_Float16)w[k * N + n] : (_Float16)0.f;
    }
    *(half8*)(dst + (size_t)tile * 512 + lane * 8) = *(half8*)v;
}

// Act-fragment read for k-step ks (rows 0..31 -> a0, 32..63 -> a1); fed to
// the MFMA *B* operand. AMODE 0: act buffer. 1: ks>=KS0 from x buffer
// (layer-5 skip concat). 2: entirely from x buffer (layer 1).
template <int AMODE, int KS0>
__device__ __forceinline__ void loadA(const _Float16* abuf,
                                      const _Float16* __restrict__ xbuf,
                                      int ks, int l31, int lhi,
                                      half8& a0, half8& a1) {
    if (AMODE == 2 || (AMODE == 1 && ks >= KS0)) {
        int c = ((AMODE == 2) ? ks : (ks - KS0)) * 16 + lhi * 8;
        a0 = *(const half8*)(xbuf + xswz(l31, c));
        a1 = *(const half8*)(xbuf + xswz(32 + l31, c));
    } else {
        int c = ks * 16 + lhi * 8;
        a0 = *(const half8*)(abuf + swz(l31, c));
        a1 = *(const half8*)(abuf + swz(32 + l31, c));
    }
}

// ---------------------------------------------------------------------------
// One fused layer: C(64x256) = relu(A(64xK) @ W + b), in-place LDS->LDS.
// R9 = R3's dual depth-2 prefetch (W ring from L2 + A ring from LDS, both one
// full 2-kstep iteration ahead) + R8's operand-swapped MFMA (W in A-slot ->
// D=C^T -> ds_write_b64 epilogue) + in-place 40KiB LDS + (256,3):
// 3 blocks/CU x 4 waves = 3 waves/SIMD with R3-grade per-wave efficiency
// (R3 per-wave throughput was 1.8x R8's; R8 showed TLP alone can't cover
// the un-prefetched per-iteration latency).
// ---------------------------------------------------------------------------
template <int KT, int AMODE, int KS0>
__device__ __forceinline__ void layerT(const _Float16* abuf,
                                       const _Float16* __restrict__ xbuf,
                                       const half8* __restrict__ wq,
                                       const float* __restrict__ bias,
                                       _Float16* obuf,
                                       int lane, int wave) {
    static_assert((KT & 1) == 0 && KT >= 4, "KT must be even >= 4");
    const int l31 = lane & 31, lhi = lane >> 5;
    // W frag (kstep ks, n-tile wave*2+n): wl[ks*512 + n*64]
    const half8* wl = wq + (wave * 2) * 64 + lane;
    floatx16 acc00 = {}, acc01 = {}, acc10 = {}, acc11 = {};  // [ni][mi]
    half8 wA0 = wl[0], wA1 = wl[64];
    half8 wB0 = wl[512], wB1 = wl[512 + 64];
    half8 aA0, aA1, aB0, aB1;
    loadA<AMODE, KS0>(abuf, xbuf, 0, l31, lhi, aA0, aA1);
    loadA<AMODE, KS0>(abuf, xbuf, 1, l31, lhi, aB0, aB1);
#pragma unroll 1
    for (int ks = 0; ks < KT - 2; ks += 2) {
        half8 nA0 = wl[(ks + 2) * 512], nA1 = wl[(ks + 2) * 512 + 64];
        half8 nB0 = wl[(ks + 3) * 512], nB1 = wl[(ks + 3) * 512 + 64];
        half8 pA0, pA1, pB0, pB1;
        loadA<AMODE, KS0>(abuf, xbuf, ks + 2, l31, lhi, pA0, pA1);
        loadA<AMODE, KS0>(abuf, xbuf, ks + 3, l31, lhi, pB0, pB1);
        acc00 = __builtin_amdgcn_mfma_f32_32x32x16_f16(wA0, aA0, acc00, 0, 0, 0);
        acc10 = __builtin_amdgcn_mfma_f32_32x32x16_f16(wA1, aA0, acc10, 0, 0, 0);
        acc01 = __builtin_amdgcn_mfma_f32_32x32x16_f16(wA0, aA1, acc01, 0, 0, 0);
        acc11 = __builtin_amdgcn_mfma_f32_32x32x16_f16(wA1, aA1, acc11, 0, 0, 0);
        acc00 = __builtin_amdgcn_mfma_f32_32x32x16_f16(wB0, aB0, acc00, 0, 0, 0);
        acc10 = __builtin_amdgcn_mfma_f32_32x32x16_f16(wB1, aB0, acc10, 0, 0, 0);
        acc01 = __builtin_amdgcn_mfma_f32_32x32x16_f16(wB0, aB1, acc01, 0, 0, 0);
        acc11 = __builtin_amdgcn_mfma_f32_32x32x16_f16(wB1, aB1, acc11, 0, 0, 0);
        aA0 = pA0; aA1 = pA1; aB0 = pB0; aB1 = pB1;
        wA0 = nA0; wA1 = nA1; wB0 = nB0; wB1 = nB1;
    }
    // tail: k-steps KT-2 (wA) and KT-1 (wB), rings already hold them
    acc00 = __builtin_amdgcn_mfma_f32_32x32x16_f16(wA0, aA0, acc00, 0, 0, 0);
    acc10 = __builtin_amdgcn_mfma_f32_32x32x16_f16(wA1, aA0, acc10, 0, 0, 0);
    acc01 = __builtin_amdgcn_mfma_f32_32x32x16_f16(wA0, aA1, acc01, 0, 0, 0);
    acc11 = __builtin_amdgcn_mfma_f32_32x32x16_f16(wA1, aA1, acc11, 0, 0, 0);
    acc00 = __builtin_amdgcn_mfma_f32_32x32x16_f16(wB0, aB0, acc00, 0, 0, 0);
    acc10 = __builtin_amdgcn_mfma_f32_32x32x16_f16(wB1, aB0, acc10, 0, 0, 0);
    acc01 = __builtin_amdgcn_mfma_f32_32x32x16_f16(wB0, aB1, acc01, 0, 0, 0);
    acc11 = __builtin_amdgcn_mfma_f32_32x32x16_f16(wB1, aB1, acc11, 0, 0, 0);
    // Bias as float4 groups (L1-resident).
    floatx4 bv[2][4];
#pragma unroll
    for (int ni = 0; ni < 2; ni++)
#pragma unroll
        for (int g = 0; g < 4; g++)
            bv[ni][g] = *(const floatx4*)(bias + wave * 64 + ni * 32 + lhi * 4 + g * 8);
    // In-place safety barrier: all waves' act-reads complete before any write.
    if (AMODE != 2) __syncthreads();
    // Epilogue: bias + relu + fp16, 4-half vector writes. D=C^T layout:
    // row m = lane&31 (+32*mi), col n = wave*64 + ni*32 + lhi*4 + g*8 + r.
#pragma unroll
    for (int ni = 0; ni < 2; ni++) {
#pragma unroll
        for (int mi = 0; mi < 2; mi++) {
            const floatx16 accv = (ni == 0) ? (mi == 0 ? acc00 : acc01)
                                            : (mi == 0 ? acc10 : acc11);
            int row = mi * 32 + l31;
#pragma unroll
            for (int g = 0; g < 4; g++) {
                int col = wave * 64 + ni * 32 + lhi * 4 + g * 8;
                half4v h;
#pragma unroll
                for (int r = 0; r < 4; r++) {
                    float v = accv[g * 4 + r] + bv[ni][g][r];
                    v = v > 0.f ? v : 0.f;
                    h[r] = (_Float16)v;
                }
                *(half4v*)(obuf + swz(row, col)) = h;
            }
        }
    }
}

// Layer 9 (swapped): 256 -> 4 (N padded to 32). Waves 0,1 take m-tiles;
// D[n][m]: lanes 0..31 hold n=r (r<4) for row m=l31 -> one float4 store/lane.
__device__ __forceinline__ void layer9T(const _Float16* abuf,
                                        const half8* __restrict__ wq,
                                        const float* __restrict__ b9,
                                        float* __restrict__ out, long r0,
                                        int lane, int wave) {
    if (wave >= 2) return;
    const int l31 = lane & 31, lhi = lane >> 5;
    floatx16 acc = {};
    const half8* wl = wq + lane;
    half8 wc = wl[0];
#pragma unroll 1
    for (int ks = 0; ks < 15; ks++) {
        half8 wn = wl[(ks + 1) * 64];
        half8 a = *(const half8*)(abuf + swz(wave * 32 + l31, ks * 16 + lhi * 8));
        acc = __builtin_amdgcn_mfma_f32_32x32x16_f16(wc, a, acc, 0, 0, 0);
        wc = wn;
    }
    {
        half8 a = *(const half8*)(abuf + swz(wave * 32 + l31, 15 * 16 + lhi * 8));
        acc = __builtin_amdgcn_mfma_f32_32x32x16_f16(wc, a, acc, 0, 0, 0);
    }
    if (lhi == 0) {
        floatx4 b4 = *(const floatx4*)(b9);
        floatx4 o;
#pragma unroll
        for (int r = 0; r < 4; r++) o[r] = acc[r] + b4[r];
        *(floatx4*)(out + (r0 + wave * 32 + l31) * 4) = o;
    }
}

__global__ __launch_bounds__(256, 3) void mlp_fused(
    const float* __restrict__ x, const _Float16* __restrict__ wpk,
    const float* __restrict__ b1, const float* __restrict__ b2,
    const float* __restrict__ b3, const float* __restrict__ b4,
    const float* __restrict__ b5, const float* __restrict__ b6,
    const float* __restrict__ b7, const float* __restrict__ b8,
    const float* __restrict__ b9, float* __restrict__ out) {
    // Single 32 KiB act buffer + 8 KiB x tile = 40960 B. (256,3): 3 blocks/CU
    // (reg-capped at 170 total/wave; LDS would allow 4) = 3 waves/SIMD with
    // the full dual prefetch ring (~64 acc + ~100 arch peak).
    __shared__ _Float16 lds[64 * 256 + 64 * 64];
    _Float16* buf = lds;
    _Float16* xbuf = lds + 64 * 256;
    const int tid = threadIdx.x;
    const int lane = tid & 63, wave = tid >> 6;
    const long r0 = (long)blockIdx.x * 64;

    // Stage x: zero pad cols (39..63) and fill cols 0..38 — disjoint, one barrier.
    for (int i = tid; i < 64 * 25; i += 256) {
        int row = i / 25, col = 39 + (i - row * 25);
        xbuf[xswz(row, col)] = (_Float16)0.f;
    }
    for (int i = tid; i < 64 * 39; i += 256) {
        int row = i / 39, col = i - row * 39;
        xbuf[xswz(row, col)] = (_Float16)x[r0 * 39 + i];  // contiguous 2496 floats
    }
    __syncthreads();

    const half8* wp = (const half8*)wpk;  // tile = 64 half8 (1 KB)
    const half8* w1q = wp + (size_t)0 * 64;
    const half8* w2q = wp + (size_t)32 * 64;
    const half8* w3q = wp + (size_t)160 * 64;
    const half8* w4q = wp + (size_t)288 * 64;
    const half8* w5q = wp + (size_t)416 * 64;
    const half8* w6q = wp + (size_t)576 * 64;
    const half8* w7q = wp + (size_t)704 * 64;
    const half8* w8q = wp + (size_t)832 * 64;
    const half8* w9q = wp + (size_t)960 * 64;

    layerT<4, 2, 0>(xbuf, xbuf, w1q, b1, buf, lane, wave);   // x -> buf
    __syncthreads();
    layerT<16, 0, 0>(buf, xbuf, w2q, b2, buf, lane, wave);
    __syncthreads();
    layerT<16, 0, 0>(buf, xbuf, w3q, b3, buf, lane, wave);
    __syncthreads();
    layerT<16, 0, 0>(buf, xbuf, w4q, b4, buf, lane, wave);
    __syncthreads();
    layerT<20, 1, 16>(buf, xbuf, w5q, b5, buf, lane, wave);  // [h|x] skip
    __syncthreads();
    layerT<16, 0, 0>(buf, xbuf, w6q, b6, buf, lane, wave);
    __syncthreads();
    layerT<16, 0, 0>(buf, xbuf, w7q, b7, buf, lane, wave);
    __syncthreads();
    layerT<16, 0, 0>(buf, xbuf, w8q, b8, buf, lane, wave);
    __syncthreads();
    layer9T(buf, w9q, b9, out, r0, lane, wave);
}

extern "C" void kernel_launch(void* const* d_in, const int* in_sizes, int n_in,
                              void* d_out, int out_size, void* d_ws, size_t ws_size,
                              hipStream_t stream) {
    const float* x = (const float*)d_in[0];
    const float* w[9];
    const float* b[9];
    for (int i = 0; i < 9; i++) {
        w[i] = (const float*)d_in[1 + 2 * i];
        b[i] = (const float*)d_in[2 + 2 * i];
    }
    _Float16* wpk = (_Float16*)d_ws;  // 999424 B

    pack_w32<<<244, 256, 0, stream>>>(w[0], w[1], w[2], w[3], w[4], w[5], w[6], w[7], w[8], wpk);
    mlp_fused<<<262144 / 64, 256, 0, stream>>>(x, wpk, b[0], b[1], b[2], b[3], b[4],
                                               b[5], b[6], b[7], b[8], (float*)d_out);
}

// Round 10
// 378.788 us; speedup vs baseline: 1.2130x; 1.2130x over previous
//
#include <hip/hip_runtime.h>
#include <hip/hip_bf16.h>

typedef _Float16 half8 __attribute__((ext_vector_type(8)));
typedef _Float16 half4v __attribute__((ext_vector_type(4)));
typedef float floatx4 __attribute__((ext_vector_type(4)));
typedef float floatx16 __attribute__((ext_vector_type(16)));

// ---------------------------------------------------------------------------
// Swizzled LDS layouts (chunk = 8 halfs = 16B, rotated by row).
// act buffer: 64x256 fp16 (32 KiB, single, in-place read->barrier->write).
// x buffer: 64x64 fp16 (8 KiB). Total 40960 B -> 4 blocks/CU.
// ---------------------------------------------------------------------------
__device__ __forceinline__ int swz(int row, int col) {
    return row * 256 + ((((col >> 3) + row) & 31) << 3) + (col & 7);
}
__device__ __forceinline__ int xswz(int row, int col) {
    return row * 64 + ((((col >> 3) + row) & 7) << 3) + (col & 7);
}

// ---------------------------------------------------------------------------
// Weight pre-pack (numerically proven R5-R9): fp32 (K,N) row-major -> fp16
// fragment order; lane L holds W[kt*16 + 8*(L>>5) + j][nt*32 + (L&31)].
// Fed to the MFMA *A* operand so D = C^T (proven R8/R9).
// K zero-padded: L1 39->64 (KT=4), L5 295->320 (KT=20), others 256 (KT=16).
// L9 N 4->32. Tile starts (1KB tiles): {0,32,160,288,416,576,704,832,960},
// total 976 tiles = 999424 B in d_ws.
// ---------------------------------------------------------------------------
__global__ void pack_w32(const float* __restrict__ w1, const float* __restrict__ w2,
                         const float* __restrict__ w3, const float* __restrict__ w4,
                         const float* __restrict__ w5, const float* __restrict__ w6,
                         const float* __restrict__ w7, const float* __restrict__ w8,
                         const float* __restrict__ w9, _Float16* __restrict__ dst) {
    const int tileStart[10] = {0, 32, 160, 288, 416, 576, 704, 832, 960, 976};
    const int Ks[9] = {39, 256, 256, 256, 295, 256, 256, 256, 256};
    const int Ns[9] = {256, 256, 256, 256, 256, 256, 256, 256, 4};
    const int Tn[9] = {8, 8, 8, 8, 8, 8, 8, 8, 1};
    const float* ws[9] = {w1, w2, w3, w4, w5, w6, w7, w8, w9};

    int g = blockIdx.x * blockDim.x + threadIdx.x;
    int tile = g >> 6, lane = g & 63;
    if (tile >= 976) return;
    int layer = 0;
    while (tile >= tileStart[layer + 1]) layer++;
    int t = tile - tileStart[layer];
    int tn = Tn[layer];
    int kt = t / tn, nt = t - kt * tn;
    int k0 = kt * 16 + (lane >> 5) * 8;
    int n = nt * 32 + (lane & 31);
    const float* w = ws[layer];
    int K = Ks[layer], N = Ns[layer];
    _Float16 v[8];
#pragma unroll
    for (int j = 0; j < 8; j++) {
        int k = k0 + j;
        v[j] = (k < K && n < N) ? (_Float16)w[k * N + n] : (_Float16)0.f;
    }
    *(half8*)(dst + (size_t)tile * 512 + lane * 8) = *(half8*)v;
}

// Act-fragment read for k-step ks (rows 0..31 -> a0, 32..63 -> a1); fed to
// the MFMA *B* operand. AMODE 0: act buffer. 1: ks>=KS0 from x buffer
// (layer-5 skip concat). 2: entirely from x buffer (layer 1).
template <int AMODE, int KS0>
__device__ __forceinline__ void loadA(const _Float16* abuf,
                                      const _Float16* __restrict__ xbuf,
                                      int ks, int l31, int lhi,
                                      half8& a0, half8& a1) {
    if (AMODE == 2 || (AMODE == 1 && ks >= KS0)) {
        int c = ((AMODE == 2) ? ks : (ks - KS0)) * 16 + lhi * 8;
        a0 = *(const half8*)(xbuf + xswz(l31, c));
        a1 = *(const half8*)(xbuf + xswz(32 + l31, c));
    } else {
        int c = ks * 16 + lhi * 8;
        a0 = *(const half8*)(abuf + swz(l31, c));
        a1 = *(const half8*)(abuf + swz(32 + l31, c));
    }
}

// ---------------------------------------------------------------------------
// One fused layer: C(64x256) = relu(A(64xK) @ W + b), in-place LDS->LDS.
// R10 = R8 (2m x 2n swapped-operand tile, b64 epilogue, 40KiB LDS, (256,4) ->
// 16 waves/CU) + R5's depth-2 W prefetch ring (next 2 ksteps' W always in
// flight; A read in-iteration) + THE KEY FIX: bias loads moved after the
// barrier behind an asm memory fence. In R8 the loop-invariant bias float4s
// (32 VGPRs) were hoisted above the k-loop, eating the exact register
// headroom every prefetch attempt needed (R4/R7/R9 all spilled). Steady-state
// arch regs now: W ring 32 + A transient 8 + addr ~16 = ~56 <= 64 budget.
// ---------------------------------------------------------------------------
template <int KT, int AMODE, int KS0>
__device__ __forceinline__ void layerT(const _Float16* abuf,
                                       const _Float16* __restrict__ xbuf,
                                       const half8* __restrict__ wq,
                                       const float* __restrict__ bias,
                                       _Float16* obuf,
                                       int lane, int wave) {
    static_assert((KT & 1) == 0 && KT >= 4, "KT must be even >= 4");
    const int l31 = lane & 31, lhi = lane >> 5;
    // W frag (kstep ks, n-tile wave*2+n): wl[ks*512 + n*64]
    const half8* wl = wq + (wave * 2) * 64 + lane;
    floatx16 acc00 = {}, acc01 = {}, acc10 = {}, acc11 = {};  // [ni][mi]
    half8 wA0 = wl[0], wA1 = wl[64];
    half8 wB0 = wl[512], wB1 = wl[512 + 64];
#pragma unroll 1
    for (int ks = 0; ks < KT - 2; ks += 2) {
        half8 nA0 = wl[(ks + 2) * 512], nA1 = wl[(ks + 2) * 512 + 64];
        half8 nB0 = wl[(ks + 3) * 512], nB1 = wl[(ks + 3) * 512 + 64];
        half8 a0, a1;
        loadA<AMODE, KS0>(abuf, xbuf, ks, l31, lhi, a0, a1);
        acc00 = __builtin_amdgcn_mfma_f32_32x32x16_f16(wA0, a0, acc00, 0, 0, 0);
        acc10 = __builtin_amdgcn_mfma_f32_32x32x16_f16(wA1, a0, acc10, 0, 0, 0);
        acc01 = __builtin_amdgcn_mfma_f32_32x32x16_f16(wA0, a1, acc01, 0, 0, 0);
        acc11 = __builtin_amdgcn_mfma_f32_32x32x16_f16(wA1, a1, acc11, 0, 0, 0);
        loadA<AMODE, KS0>(abuf, xbuf, ks + 1, l31, lhi, a0, a1);
        acc00 = __builtin_amdgcn_mfma_f32_32x32x16_f16(wB0, a0, acc00, 0, 0, 0);
        acc10 = __builtin_amdgcn_mfma_f32_32x32x16_f16(wB1, a0, acc10, 0, 0, 0);
        acc01 = __builtin_amdgcn_mfma_f32_32x32x16_f16(wB0, a1, acc01, 0, 0, 0);
        acc11 = __builtin_amdgcn_mfma_f32_32x32x16_f16(wB1, a1, acc11, 0, 0, 0);
        wA0 = nA0; wA1 = nA1; wB0 = nB0; wB1 = nB1;
    }
    {   // tail: k-steps KT-2 (wA) and KT-1 (wB), already in the ring
        half8 a0, a1;
        loadA<AMODE, KS0>(abuf, xbuf, KT - 2, l31, lhi, a0, a1);
        acc00 = __builtin_amdgcn_mfma_f32_32x32x16_f16(wA0, a0, acc00, 0, 0, 0);
        acc10 = __builtin_amdgcn_mfma_f32_32x32x16_f16(wA1, a0, acc10, 0, 0, 0);
        acc01 = __builtin_amdgcn_mfma_f32_32x32x16_f16(wA0, a1, acc01, 0, 0, 0);
        acc11 = __builtin_amdgcn_mfma_f32_32x32x16_f16(wA1, a1, acc11, 0, 0, 0);
        loadA<AMODE, KS0>(abuf, xbuf, KT - 1, l31, lhi, a0, a1);
        acc00 = __builtin_amdgcn_mfma_f32_32x32x16_f16(wB0, a0, acc00, 0, 0, 0);
        acc10 = __builtin_amdgcn_mfma_f32_32x32x16_f16(wB1, a0, acc10, 0, 0, 0);
        acc01 = __builtin_amdgcn_mfma_f32_32x32x16_f16(wB0, a1, acc01, 0, 0, 0);
        acc11 = __builtin_amdgcn_mfma_f32_32x32x16_f16(wB1, a1, acc11, 0, 0, 0);
    }
    // In-place safety barrier: all waves' act-reads complete before any write.
    if (AMODE != 2) __syncthreads();
    // Anti-hoist fence: bias loads must NOT be hoisted above the k-loop
    // (they cost 32 VGPRs of loop-live range — R8's hidden register eater).
    asm volatile("" ::: "memory");
    floatx4 bv[2][4];
#pragma unroll
    for (int ni = 0; ni < 2; ni++)
#pragma unroll
        for (int g = 0; g < 4; g++)
            bv[ni][g] = *(const floatx4*)(bias + wave * 64 + ni * 32 + lhi * 4 + g * 8);
    // Epilogue: bias + relu + fp16, 4-half vector writes. D=C^T layout:
    // row m = lane&31 (+32*mi), col n = wave*64 + ni*32 + lhi*4 + g*8 + r.
#pragma unroll
    for (int ni = 0; ni < 2; ni++) {
#pragma unroll
        for (int mi = 0; mi < 2; mi++) {
            const floatx16 accv = (ni == 0) ? (mi == 0 ? acc00 : acc01)
                                            : (mi == 0 ? acc10 : acc11);
            int row = mi * 32 + l31;
#pragma unroll
            for (int g = 0; g < 4; g++) {
                int col = wave * 64 + ni * 32 + lhi * 4 + g * 8;
                half4v h;
#pragma unroll
                for (int r = 0; r < 4; r++) {
                    float v = accv[g * 4 + r] + bv[ni][g][r];
                    v = v > 0.f ? v : 0.f;
                    h[r] = (_Float16)v;
                }
                *(half4v*)(obuf + swz(row, col)) = h;
            }
        }
    }
}

// Layer 9 (swapped): 256 -> 4 (N padded to 32). Waves 0,1 take m-tiles;
// D[n][m]: lanes 0..31 hold n=r (r<4) for row m=l31 -> one float4 store/lane.
__device__ __forceinline__ void layer9T(const _Float16* abuf,
                                        const half8* __restrict__ wq,
                                        const float* __restrict__ b9,
                                        float* __restrict__ out, long r0,
                                        int lane, int wave) {
    if (wave >= 2) return;
    const int l31 = lane & 31, lhi = lane >> 5;
    floatx16 acc = {};
    const half8* wl = wq + lane;
    half8 wc = wl[0];
#pragma unroll 1
    for (int ks = 0; ks < 15; ks++) {
        half8 wn = wl[(ks + 1) * 64];
        half8 a = *(const half8*)(abuf + swz(wave * 32 + l31, ks * 16 + lhi * 8));
        acc = __builtin_amdgcn_mfma_f32_32x32x16_f16(wc, a, acc, 0, 0, 0);
        wc = wn;
    }
    {
        half8 a = *(const half8*)(abuf + swz(wave * 32 + l31, 15 * 16 + lhi * 8));
        acc = __builtin_amdgcn_mfma_f32_32x32x16_f16(wc, a, acc, 0, 0, 0);
    }
    if (lhi == 0) {
        asm volatile("" ::: "memory");
        floatx4 b4 = *(const floatx4*)(b9);
        floatx4 o;
#pragma unroll
        for (int r = 0; r < 4; r++) o[r] = acc[r] + b4[r];
        *(floatx4*)(out + (r0 + wave * 32 + l31) * 4) = o;
    }
}

__global__ __launch_bounds__(256, 4) void mlp_fused(
    const float* __restrict__ x, const _Float16* __restrict__ wpk,
    const float* __restrict__ b1, const float* __restrict__ b2,
    const float* __restrict__ b3, const float* __restrict__ b4,
    const float* __restrict__ b5, const float* __restrict__ b6,
    const float* __restrict__ b7, const float* __restrict__ b8,
    const float* __restrict__ b9, float* __restrict__ out) {
    // Single 32 KiB act buffer + 8 KiB x tile = 40960 B; 4-wave blocks;
    // 4 blocks/CU = 16 waves/CU = 4 waves/SIMD at <=128 total regs/wave.
    __shared__ _Float16 lds[64 * 256 + 64 * 64];
    _Float16* buf = lds;
    _Float16* xbuf = lds + 64 * 256;
    const int tid = threadIdx.x;
    const int lane = tid & 63, wave = tid >> 6;
    const long r0 = (long)blockIdx.x * 64;

    // Stage x: zero pad cols (39..63) and fill cols 0..38 — disjoint, one barrier.
    for (int i = tid; i < 64 * 25; i += 256) {
        int row = i / 25, col = 39 + (i - row * 25);
        xbuf[xswz(row, col)] = (_Float16)0.f;
    }
    for (int i = tid; i < 64 * 39; i += 256) {
        int row = i / 39, col = i - row * 39;
        xbuf[xswz(row, col)] = (_Float16)x[r0 * 39 + i];  // contiguous 2496 floats
    }
    __syncthreads();

    const half8* wp = (const half8*)wpk;  // tile = 64 half8 (1 KB)
    const half8* w1q = wp + (size_t)0 * 64;
    const half8* w2q = wp + (size_t)32 * 64;
    const half8* w3q = wp + (size_t)160 * 64;
    const half8* w4q = wp + (size_t)288 * 64;
    const half8* w5q = wp + (size_t)416 * 64;
    const half8* w6q = wp + (size_t)576 * 64;
    const half8* w7q = wp + (size_t)704 * 64;
    const half8* w8q = wp + (size_t)832 * 64;
    const half8* w9q = wp + (size_t)960 * 64;

    layerT<4, 2, 0>(xbuf, xbuf, w1q, b1, buf, lane, wave);   // x -> buf
    __syncthreads();
    layerT<16, 0, 0>(buf, xbuf, w2q, b2, buf, lane, wave);
    __syncthreads();
    layerT<16, 0, 0>(buf, xbuf, w3q, b3, buf, lane, wave);
    __syncthreads();
    layerT<16, 0, 0>(buf, xbuf, w4q, b4, buf, lane, wave);
    __syncthreads();
    layerT<20, 1, 16>(buf, xbuf, w5q, b5, buf, lane, wave);  // [h|x] skip
    __syncthreads();
    layerT<16, 0, 0>(buf, xbuf, w6q, b6, buf, lane, wave);
    __syncthreads();
    layerT<16, 0, 0>(buf, xbuf, w7q, b7, buf, lane, wave);
    __syncthreads();
    layerT<16, 0, 0>(buf, xbuf, w8q, b8, buf, lane, wave);
    __syncthreads();
    layer9T(buf, w9q, b9, out, r0, lane, wave);
}

extern "C" void kernel_launch(void* const* d_in, const int* in_sizes, int n_in,
                              void* d_out, int out_size, void* d_ws, size_t ws_size,
                              hipStream_t stream) {
    const float* x = (const float*)d_in[0];
    const float* w[9];
    const float* b[9];
    for (int i = 0; i < 9; i++) {
        w[i] = (const float*)d_in[1 + 2 * i];
        b[i] = (const float*)d_in[2 + 2 * i];
    }
    _Float16* wpk = (_Float16*)d_ws;  // 999424 B

    pack_w32<<<244, 256, 0, stream>>>(w[0], w[1], w[2], w[3], w[4], w[5], w[6], w[7], w[8], wpk);
    mlp_fused<<<262144 / 64, 256, 0, stream>>>(x, wpk, b[0], b[1], b[2], b[3], b[4],
                                               b[5], b[6], b[7], b[8], (float*)d_out);
}